// Round 1
// baseline (2609.836 us; speedup 1.0000x reference)
//
#include <hip/hip_runtime.h>
#include <math.h>

#define ZB 16
#define NATOMS 192
#define NBAS 40
#define ZA (ZB*NATOMS)       // 3072
#define ATILE 12
#define BTILE 16
#define NTILES_B (NATOMS/BTILE)   // 12

__device__ __forceinline__ float softplus5(float x){
    float t = 5.f*x;
    return (t < 80.f) ? log1pf(expf(t)) : t;
}
__device__ __forceinline__ float sspf(float x){   // shifted softplus (beta=5), ssp(0)=0
    return 0.2f*softplus5(x) - 0.13862943611198906f;
}
__device__ __forceinline__ float spf(float x){    // softplus (beta=5)
    return 0.2f*softplus5(x);
}

// ---------------- encoders: f_bio = feat[:,:,:7]@W_bio + b_bio ; f_ch = feat[:,:,7]*W_ch + b_ch
__global__ void k_encode(const float* __restrict__ feat, const float* __restrict__ Wb,
                         const float* __restrict__ bb, const float* __restrict__ Wc,
                         const float* __restrict__ bc, float* __restrict__ fbio,
                         float* __restrict__ fch){
    int za = blockIdx.x; int e = threadIdx.x;      // 64 threads
    const float* fr = feat + za*8;
    float accb = bb[e];
    #pragma unroll
    for (int c = 0; c < 7; c++) accb += fr[c]*Wb[c*64+e];
    float accc = bc[e] + fr[7]*Wc[e];
    fbio[za*64+e] = accb;
    fch[za*64+e]  = accc;
}

// ---------------- transpose rWo [4096][64] -> rWoT [64][4096]
__global__ void k_transpose(const float* __restrict__ in, float* __restrict__ out){
    __shared__ float t[64][65];
    int hj0 = blockIdx.x*64;
    int lane = threadIdx.x & 63, grp = threadIdx.x >> 6;  // 256 threads
    for (int r = grp; r < 64; r += 4) t[r][lane] = in[(hj0+r)*64 + lane];
    __syncthreads();
    for (int r = grp; r < 64; r += 4) out[r*4096 + hj0 + lane] = t[lane][r];
}

// ---------------- tmp GEMM: C[m=s*3072+z*192+b][hj] = sum_i fm[m][i] * rWoT[i][hj]
// fm = f * mask * (1/sqrt(192)) ; M=6144, N=4096, K=64
__global__ void k_tmp(const float* __restrict__ fbio, const float* __restrict__ fch,
                      const float* __restrict__ mask, const float* __restrict__ Bt,
                      float* __restrict__ tmp){
    __shared__ float As[64*65];
    __shared__ float Bs[64*65];
    int m0 = blockIdx.x*64, n0 = blockIdx.y*64;
    int tid = threadIdx.x;   // 256
    for (int i = tid; i < 4096; i += 256){
        int r = i >> 6, k = i & 63;
        int m = m0 + r;
        int s = (m >= ZA) ? 1 : 0;
        int zb = m - s*ZA;
        const float* f = s ? fch : fbio;
        As[r*65+k] = f[zb*64+k] * mask[zb] * 0.07216878364870322f;
        Bs[r*65+k] = Bt[r*4096 + n0 + k];
    }
    __syncthreads();
    int tx = tid & 15, ty = tid >> 4;
    float acc[4][4] = {};
    #pragma unroll 8
    for (int k = 0; k < 64; k++){
        float av[4], bv[4];
        #pragma unroll
        for (int r = 0; r < 4; r++) av[r] = As[(ty*4+r)*65 + k];
        #pragma unroll
        for (int c = 0; c < 4; c++) bv[c] = Bs[k*65 + tx*4 + c];
        #pragma unroll
        for (int r = 0; r < 4; r++)
            #pragma unroll
            for (int c = 0; c < 4; c++) acc[r][c] += av[r]*bv[c];
    }
    #pragma unroll
    for (int r = 0; r < 4; r++){
        float4 v = make_float4(acc[r][0], acc[r][1], acc[r][2], acc[r][3]);
        *(float4*)&tmp[(size_t)(m0+ty*4+r)*4096 + n0 + tx*4] = v;
    }
}

// ---------------- fused conv: per (z, a-tile) block; compute R on the fly, contract vs tmp
// out_s[z,a,j] = sum_{b,h} R[z,a,b,h] * tmp_s[z,b,h,j]; epilogue f_next = mask*sp(out)
#define ACC24(R0,R1,R2,TB,TC) \
    accB[0]+=R0.x*TB; accB[1]+=R0.y*TB; accB[2]+=R0.z*TB; accB[3]+=R0.w*TB; \
    accB[4]+=R1.x*TB; accB[5]+=R1.y*TB; accB[6]+=R1.z*TB; accB[7]+=R1.w*TB; \
    accB[8]+=R2.x*TB; accB[9]+=R2.y*TB; accB[10]+=R2.z*TB; accB[11]+=R2.w*TB; \
    accC[0]+=R0.x*TC; accC[1]+=R0.y*TC; accC[2]+=R0.z*TC; accC[3]+=R0.w*TC; \
    accC[4]+=R1.x*TC; accC[5]+=R1.y*TC; accC[6]+=R1.z*TC; accC[7]+=R1.w*TC; \
    accC[8]+=R2.x*TC; accC[9]+=R2.y*TC; accC[10]+=R2.z*TC; accC[11]+=R2.w*TC;

__global__ __launch_bounds__(256,2) void k_conv(
    const float* __restrict__ geom, const float* __restrict__ mask,
    const float* __restrict__ rW1, const float* __restrict__ rb1,
    const float* __restrict__ rW2, const float* __restrict__ rb2,
    const float* __restrict__ tmp,          // [2][ZA][4096]
    float* __restrict__ obio, float* __restrict__ och)
{
    __shared__ float4 R4[BTILE*64*3];       // R tile [b][h][a(12)] as float4x3 = 48 KiB
    __shared__ float w1s[NBAS*65];          // rW1 padded rows (bank-spread on k0)
    __shared__ float rb1s[64], rb2s[64];
    __shared__ float gB[NATOMS*3];
    __shared__ float gA[ATILE*3];
    float* Rf = (float*)R4;

    int tid = threadIdx.x;
    int z = blockIdx.x & 15, at = blockIdx.x >> 4;

    for (int i = tid; i < NBAS*64; i += 256){ int k = i >> 6, h = i & 63; w1s[k*65+h] = rW1[i]; }
    if (tid < 64){ rb1s[tid] = rb1[tid]; rb2s[tid] = rb2[tid]; }
    for (int i = tid; i < NATOMS*3; i += 256) gB[i] = geom[z*NATOMS*3 + i];
    if (tid < ATILE*3) gA[tid] = geom[(z*NATOMS + at*ATILE)*3 + tid];

    const float* tmpB = tmp;
    const float* tmpC = tmp + (size_t)ZA*4096;

    float accB[ATILE] = {}, accC[ATILE] = {};
    int j = tid & 63, wg = tid >> 6;

    for (int t = 0; t < NTILES_B; t++){
        __syncthreads();
        // ---- phase A: radial MLP for 12a x 16b pairs (192 threads)
        if (tid < ATILE*BTILE){
            int a_l = tid % ATILE, b_l = tid / ATILE;
            int b = t*BTILE + b_l;
            float dx = gA[a_l*3+0]-gB[b*3+0];
            float dy = gA[a_l*3+1]-gB[b*3+1];
            float dz = gA[a_l*3+2]-gB[b*3+2];
            float r = sqrtf(dx*dx+dy*dy+dz*dz);
            float u = r * 3.9f;                 // r/step, step=10/39
            int k0 = (int)u;                    // floor, u>=0
            float fr = u - (float)k0;
            float cs = cosf(fr * 1.57079632679489662f);
            float sn = sinf(fr * 1.57079632679489662f);
            float c0 = cs*cs, c1 = sn*sn;       // only 2 basis bumps are nonzero
            if (k0   >= NBAS) c0 = 0.f;
            if (k0+1 >= NBAS) c1 = 0.f;
            int kk0 = min(k0, NBAS-1), kk1 = min(k0+1, NBAS-1);
            float h1[64];
            #pragma unroll
            for (int h = 0; h < 64; h++){
                float pre = rb1s[h] + c0*w1s[kk0*65+h] + c1*w1s[kk1*65+h];
                h1[h] = sspf(pre);
            }
            int wbase = b_l*64;
            for (int ho = 0; ho < 64; ho += 4){
                float a0 = rb2s[ho], a1 = rb2s[ho+1], a2 = rb2s[ho+2], a3 = rb2s[ho+3];
                #pragma unroll
                for (int hi = 0; hi < 64; hi++){
                    float x = h1[hi];
                    const float* wrow = rW2 + hi*64 + ho;   // wave-uniform -> s_load
                    a0 += x*wrow[0]; a1 += x*wrow[1]; a2 += x*wrow[2]; a3 += x*wrow[3];
                }
                Rf[(wbase+ho  )*12 + a_l] = sspf(a0);
                Rf[(wbase+ho+1)*12 + a_l] = sspf(a1);
                Rf[(wbase+ho+2)*12 + a_l] = sspf(a2);
                Rf[(wbase+ho+3)*12 + a_l] = sspf(a3);
            }
        }
        __syncthreads();
        // ---- phase B: contraction; wave wg handles 4 b's, lane j holds output col
        #pragma unroll
        for (int bb = 0; bb < 4; bb++){
            int b_l = wg*4 + bb;
            int b = t*BTILE + b_l;
            const float* pB = tmpB + (size_t)(z*NATOMS + b)*4096 + j;
            const float* pC = tmpC + (size_t)(z*NATOMS + b)*4096 + j;
            int rbase = b_l*64*3;
            #pragma unroll 8
            for (int h = 0; h < 64; h++){
                float4 r0 = R4[rbase + h*3 + 0];   // broadcast reads (all lanes same addr)
                float4 r1 = R4[rbase + h*3 + 1];
                float4 r2 = R4[rbase + h*3 + 2];
                float tb = pB[h*64];
                float tc = pC[h*64];
                ACC24(r0, r1, r2, tb, tc)
            }
        }
    }
    // ---- reduce over the 4 waves + epilogue sp()*mask
    int a0g = at*ATILE;
    __syncthreads();
    #pragma unroll
    for (int a = 0; a < ATILE; a++) Rf[(wg*ATILE + a)*64 + j] = accB[a];
    __syncthreads();
    for (int idx = tid; idx < ATILE*64; idx += 256){
        int a = idx >> 6, jj = idx & 63;
        float s = Rf[(0*ATILE+a)*64+jj] + Rf[(1*ATILE+a)*64+jj]
                + Rf[(2*ATILE+a)*64+jj] + Rf[(3*ATILE+a)*64+jj];
        obio[(z*NATOMS + a0g + a)*64 + jj] = spf(s) * mask[z*NATOMS + a0g + a];
    }
    __syncthreads();
    #pragma unroll
    for (int a = 0; a < ATILE; a++) Rf[(wg*ATILE + a)*64 + j] = accC[a];
    __syncthreads();
    for (int idx = tid; idx < ATILE*64; idx += 256){
        int a = idx >> 6, jj = idx & 63;
        float s = Rf[(0*ATILE+a)*64+jj] + Rf[(1*ATILE+a)*64+jj]
                + Rf[(2*ATILE+a)*64+jj] + Rf[(3*ATILE+a)*64+jj];
        och[(z*NATOMS + a0g + a)*64 + jj] = spf(s) * mask[z*NATOMS + a0g + a];
    }
}

// ---------------- head: y1 = concat(fbio,fch) @ fW1 + fb1   (4 rows per block)
__global__ void k_h1(const float* __restrict__ fbio, const float* __restrict__ fch,
                     const float* __restrict__ fW1, const float* __restrict__ fb1,
                     float* __restrict__ y1){
    __shared__ float xr[4][128];
    int r0 = blockIdx.x*4, tid = threadIdx.x;   // 128 threads
    for (int i = tid; i < 512; i += 128){
        int r = i >> 7, c = i & 127;
        int row = r0 + r;
        xr[r][c] = (c < 64) ? fbio[row*64 + c] : fch[row*64 + c - 64];
    }
    __syncthreads();
    int k = tid;
    float b = fb1[k];
    float a0 = b, a1 = b, a2 = b, a3 = b;
    #pragma unroll 8
    for (int c = 0; c < 128; c++){
        float w = fW1[c*128 + k];
        a0 += xr[0][c]*w; a1 += xr[1][c]*w; a2 += xr[2][c]*w; a3 += xr[3][c]*w;
    }
    y1[(r0+0)*128+k] = a0; y1[(r0+1)*128+k] = a1;
    y1[(r0+2)*128+k] = a2; y1[(r0+3)*128+k] = a3;
}

// ---------------- BN over (z,feat) per atom + leaky(0.2), in place on y1 [ZA][128]
__global__ void k_bn1(float* __restrict__ y1){
    int a = blockIdx.x, tid = threadIdx.x;   // 256 threads, 2048 vals
    float v[8]; float s = 0.f, ss = 0.f;
    #pragma unroll
    for (int i = 0; i < 8; i++){
        int e = tid + i*256;
        int zz = e >> 7, k = e & 127;
        float x = y1[(zz*NATOMS + a)*128 + k];
        v[i] = x; s += x; ss += x*x;
    }
    for (int off = 32; off; off >>= 1){ s += __shfl_down(s, off); ss += __shfl_down(ss, off); }
    __shared__ float wsum[8]; __shared__ float stats[2];
    int lane = tid & 63, w = tid >> 6;
    if (!lane){ wsum[w] = s; wsum[4+w] = ss; }
    __syncthreads();
    if (!tid){
        float S = wsum[0]+wsum[1]+wsum[2]+wsum[3];
        float SS = wsum[4]+wsum[5]+wsum[6]+wsum[7];
        float m = S*(1.f/2048.f);
        float var = SS*(1.f/2048.f) - m*m;
        stats[0] = m; stats[1] = rsqrtf(var + 1e-5f);
    }
    __syncthreads();
    float m = stats[0], inv = stats[1];
    #pragma unroll
    for (int i = 0; i < 8; i++){
        int e = tid + i*256;
        int zz = e >> 7, k = e & 127;
        float x = (v[i]-m)*inv;
        x = (x > 0.f) ? x : 0.2f*x;
        y1[(zz*NATOMS + a)*128 + k] = x;
    }
}

// ---------------- y2 = y1 @ fW2 + fb2   (4 rows per block)
__global__ void k_h2(const float* __restrict__ y1, const float* __restrict__ fW2,
                     const float* __restrict__ fb2, float* __restrict__ y2){
    __shared__ float xr[4][128];
    int r0 = blockIdx.x*4, tid = threadIdx.x;  // 128 threads
    for (int i = tid; i < 512; i += 128){ int r = i >> 7, c = i & 127; xr[r][c] = y1[(r0+r)*128 + c]; }
    __syncthreads();
    int jj = tid & 31, r = tid >> 5;
    float acc = fb2[jj];
    #pragma unroll 8
    for (int c = 0; c < 128; c++) acc += xr[r][c]*fW2[c*32 + jj];
    y2[(r0+r)*32 + jj] = acc;
}

// ---------------- BN2 per atom over (z,32) + leaky + mask, in place on y2 [ZA][32]
__global__ void k_bn2(float* __restrict__ y2, const float* __restrict__ mask){
    int a = blockIdx.x, tid = threadIdx.x;   // 256 threads, 512 vals
    int e0 = tid, e1 = tid + 256;
    int z0 = e0 >> 5, j0 = e0 & 31, z1 = e1 >> 5, j1 = e1 & 31;
    float v0 = y2[(z0*NATOMS + a)*32 + j0];
    float v1 = y2[(z1*NATOMS + a)*32 + j1];
    float s = v0 + v1, ss = v0*v0 + v1*v1;
    for (int off = 32; off; off >>= 1){ s += __shfl_down(s, off); ss += __shfl_down(ss, off); }
    __shared__ float wsum[8]; __shared__ float stats[2];
    int lane = tid & 63, w = tid >> 6;
    if (!lane){ wsum[w] = s; wsum[4+w] = ss; }
    __syncthreads();
    if (!tid){
        float S = wsum[0]+wsum[1]+wsum[2]+wsum[3];
        float SS = wsum[4]+wsum[5]+wsum[6]+wsum[7];
        float m = S*(1.f/512.f);
        float var = SS*(1.f/512.f) - m*m;
        stats[0] = m; stats[1] = rsqrtf(var + 1e-5f);
    }
    __syncthreads();
    float m = stats[0], inv = stats[1];
    float x0 = (v0-m)*inv; x0 = (x0 > 0.f) ? x0 : 0.2f*x0; x0 *= mask[z0*NATOMS + a];
    float x1 = (v1-m)*inv; x1 = (x1 > 0.f) ? x1 : 0.2f*x1; x1 *= mask[z1*NATOMS + a];
    y2[(z0*NATOMS + a)*32 + j0] = x0;
    y2[(z1*NATOMS + a)*32 + j1] = x1;
}

// ---------------- out[z,j] = sum_a y2[z,a,j]
__global__ void k_sum(const float* __restrict__ y2, float* __restrict__ out){
    int e = blockIdx.x;           // 512 outputs
    int z = e >> 5, jj = e & 31;
    int tid = threadIdx.x;        // 64
    float s = 0.f;
    for (int a = tid; a < NATOMS; a += 64) s += y2[(z*NATOMS + a)*32 + jj];
    for (int off = 32; off; off >>= 1) s += __shfl_down(s, off);
    if (!tid) out[e] = s;
}

extern "C" void kernel_launch(void* const* d_in, const int* in_sizes, int n_in,
                              void* d_out, int out_size, void* d_ws, size_t ws_size,
                              hipStream_t stream){
    const float* features = (const float*)d_in[0];
    const float* geometry = (const float*)d_in[1];
    const float* mask     = (const float*)d_in[2];
    const float* W_bio    = (const float*)d_in[3];
    const float* b_bio    = (const float*)d_in[4];
    const float* W_ch     = (const float*)d_in[5];
    const float* b_ch     = (const float*)d_in[6];
    const float* rW1[2] = {(const float*)d_in[7],  (const float*)d_in[12]};
    const float* rb1[2] = {(const float*)d_in[8],  (const float*)d_in[13]};
    const float* rW2[2] = {(const float*)d_in[9],  (const float*)d_in[14]};
    const float* rb2[2] = {(const float*)d_in[10], (const float*)d_in[15]};
    const float* rWo[2] = {(const float*)d_in[11], (const float*)d_in[16]};
    const float* fW1 = (const float*)d_in[17];
    const float* fb1 = (const float*)d_in[18];
    const float* fW2 = (const float*)d_in[19];
    const float* fb2 = (const float*)d_in[20];

    float* ws  = (float*)d_ws;
    float* f0b = ws;                       // [ZA*64]
    float* f0c = f0b + ZA*64;
    float* f1b = f0c + ZA*64;
    float* f1c = f1b + ZA*64;
    float* tmp = f1c + ZA*64;              // [2*ZA*4096]
    float* rWoT = tmp + (size_t)2*ZA*4096; // [64*4096]
    float* y1  = rWoT + 64*4096;           // [ZA*128]
    float* y2  = y1 + ZA*128;              // [ZA*32]

    k_encode<<<ZA, 64, 0, stream>>>(features, W_bio, b_bio, W_ch, b_ch, f0b, f0c);

    dim3 gt(96, 64);
    // layer 0: f0 -> f1
    k_transpose<<<64, 256, 0, stream>>>(rWo[0], rWoT);
    k_tmp<<<gt, 256, 0, stream>>>(f0b, f0c, mask, rWoT, tmp);
    k_conv<<<256, 256, 0, stream>>>(geometry, mask, rW1[0], rb1[0], rW2[0], rb2[0], tmp, f1b, f1c);
    // layer 1: f1 -> f0
    k_transpose<<<64, 256, 0, stream>>>(rWo[1], rWoT);
    k_tmp<<<gt, 256, 0, stream>>>(f1b, f1c, mask, rWoT, tmp);
    k_conv<<<256, 256, 0, stream>>>(geometry, mask, rW1[1], rb1[1], rW2[1], rb2[1], tmp, f0b, f0c);
    // head
    k_h1<<<ZA/4, 128, 0, stream>>>(f0b, f0c, fW1, fb1, y1);
    k_bn1<<<NATOMS, 256, 0, stream>>>(y1);
    k_h2<<<ZA/4, 128, 0, stream>>>(y1, fW2, fb2, y2);
    k_bn2<<<NATOMS, 256, 0, stream>>>(y2, mask);
    k_sum<<<512, 64, 0, stream>>>(y2, (float*)d_out);
}

// Round 2
// 458.992 us; speedup vs baseline: 5.6860x; 5.6860x over previous
//
#include <hip/hip_runtime.h>
#include <math.h>

#define ZB 16
#define NATOMS 192
#define NBAS 40
#define ZA (ZB*NATOMS)       // 3072
#define CHUNKB 12            // b's per conv block
#define NCHUNK 16

typedef __attribute__((ext_vector_type(4))) float f32x4;
typedef __attribute__((ext_vector_type(8))) short bf16x8;

__device__ __forceinline__ unsigned short f2bf(float x){
    union { float f; unsigned u; } v; v.f = x;
    unsigned r = v.u + 0x7FFFu + ((v.u >> 16) & 1u);
    return (unsigned short)(r >> 16);
}
// ssp(x) = softplus(5x)/5 - ln2/5 via hw exp2/log2
__device__ __forceinline__ float sspf(float x){
    float t = 7.2134752f*x;
    float tc = fminf(t, 126.f);
    float e = __builtin_amdgcn_exp2f(tc);
    float l = __builtin_amdgcn_logf(1.f + e);   // log2
    float r = fmaf(l, 0.13862944f, -0.13862944f);
    return (t > 126.f) ? (x - 0.13862944f) : r;
}
__device__ __forceinline__ float spf_act(float x){
    float t = 7.2134752f*x;
    float tc = fminf(t, 126.f);
    float e = __builtin_amdgcn_exp2f(tc);
    float l = __builtin_amdgcn_logf(1.f + e);
    float r = l*0.13862944f;
    return (t > 126.f) ? x : r;
}

// ---------------- encoders
__global__ void k_encode(const float* __restrict__ feat, const float* __restrict__ Wb,
                         const float* __restrict__ bb, const float* __restrict__ Wc,
                         const float* __restrict__ bc, float* __restrict__ fbio,
                         float* __restrict__ fch){
    int za = blockIdx.x; int e = threadIdx.x;      // 64 threads
    const float* fr = feat + za*8;
    float accb = bb[e];
    #pragma unroll
    for (int c = 0; c < 7; c++) accb += fr[c]*Wb[c*64+e];
    float accc = bc[e] + fr[7]*Wc[e];
    fbio[za*64+e] = accb;
    fch[za*64+e]  = accc;
}

// ---------------- tmp GEMM (fused rWo permute), bf16 out
// tmpT[(zb*2+s)*64 + j][h] = sum_i f_s[zb][i]*mask[zb]/sqrt(192) * rWo[h][j][i]
__global__ void k_tmp(const float* __restrict__ fbio, const float* __restrict__ fch,
                      const float* __restrict__ mask, const float* __restrict__ rWo,
                      unsigned short* __restrict__ tmpT){
    __shared__ float As[64*65];
    __shared__ float Bs[64*65];
    int m0 = blockIdx.x*64; int j = blockIdx.y;
    int tid = threadIdx.x;   // 256
    for (int i = tid; i < 4096; i += 256){
        int r = i >> 6, k = i & 63;
        int m = m0 + r;
        int s = (m >= ZA) ? 1 : 0;
        int zb = m - s*ZA;
        const float* f = s ? fch : fbio;
        As[r*65+k] = f[zb*64+k] * mask[zb] * 0.07216878364870322f;
    }
    for (int i = tid; i < 4096; i += 256){
        int h = i >> 6, ii = i & 63;
        Bs[ii*65 + h] = rWo[(h*64 + j)*64 + ii];
    }
    __syncthreads();
    int tx = tid & 15, ty = tid >> 4;
    float acc[4][4] = {};
    #pragma unroll 8
    for (int k = 0; k < 64; k++){
        float av[4], bv[4];
        #pragma unroll
        for (int r = 0; r < 4; r++) av[r] = As[(ty*4+r)*65 + k];
        #pragma unroll
        for (int c = 0; c < 4; c++) bv[c] = Bs[k*65 + tx*4 + c];
        #pragma unroll
        for (int r = 0; r < 4; r++)
            #pragma unroll
            for (int c = 0; c < 4; c++) acc[r][c] += av[r]*bv[c];
    }
    #pragma unroll
    for (int r = 0; r < 4; r++){
        int m = m0 + ty*4 + r;
        int s = (m >= ZA) ? 1 : 0;
        int zb = m - s*ZA;
        size_t row = (size_t)(zb*2 + s)*64 + j;
        ushort4 o;
        o.x = f2bf(acc[r][0]); o.y = f2bf(acc[r][1]);
        o.z = f2bf(acc[r][2]); o.w = f2bf(acc[r][3]);
        *(ushort4*)&tmpT[row*64 + tx*4] = o;
    }
}

// ---------------- fused radial-MLP + MFMA contraction
// grid (16 z, 16 chunk, 2 ahalf); partial out per chunk
__global__ __launch_bounds__(256,2) void k_conv(
    const float* __restrict__ geom,
    const float* __restrict__ rW1, const float* __restrict__ rb1,
    const float* __restrict__ rW2, const float* __restrict__ rb2,
    const unsigned short* __restrict__ tmpT,
    float* __restrict__ part)
{
    __shared__ float W1s[NBAS*64];            // 10240 B
    __shared__ float rb1s[64];
    __shared__ float rb2s[64];
    __shared__ unsigned short w2T[64*72];     // 9216 B  [hout][hin]
    __shared__ unsigned short A1s[96*72];     // 13824 B [a][k] (h1, then R)
    __shared__ unsigned short Bts[128*72];    // 18432 B [j2][h]
    __shared__ float pc0[96], pc1[96];
    __shared__ int   po0[96], po1[96];
    __shared__ float gAx[96], gAy[96], gAz[96];
    __shared__ float gBc[CHUNKB*3];

    int tid = threadIdx.x;
    int z = blockIdx.x, chunk = blockIdx.y, ah = blockIdx.z;
    int lane = tid & 63, w = tid >> 6;
    int q = lane >> 4, l15 = lane & 15;
    int wm = w & 1, wn = w >> 1;

    for (int i = tid; i < NBAS*64; i += 256) W1s[i] = rW1[i];
    if (tid < 64){ rb1s[tid] = rb1[tid]; rb2s[tid] = rb2[tid]; }
    for (int i = tid; i < 4096; i += 256){
        int hin = i >> 6, hout = i & 63;
        w2T[hout*72 + hin] = f2bf(rW2[i]);
    }
    int a0 = ah*96;
    if (tid < 96){
        gAx[tid] = geom[(z*NATOMS + a0 + tid)*3 + 0];
        gAy[tid] = geom[(z*NATOMS + a0 + tid)*3 + 1];
        gAz[tid] = geom[(z*NATOMS + a0 + tid)*3 + 2];
    }
    int b0 = chunk*CHUNKB;
    if (tid < CHUNKB*3) gBc[tid] = geom[(z*NATOMS + b0)*3 + tid];

    f32x4 acc4[12];
    #pragma unroll
    for (int i = 0; i < 12; i++) acc4[i] = (f32x4){0.f,0.f,0.f,0.f};

    __syncthreads();
    float bias1 = rb1s[lane];

    for (int bb = 0; bb < CHUNKB; bb++){
        // stage next B-tile into regs (16KB contiguous)
        const uint4* gsrc = (const uint4*)(tmpT + (size_t)((z*NATOMS + b0 + bb)*128) * 64);
        uint4 breg[4];
        #pragma unroll
        for (int it = 0; it < 4; it++) breg[it] = gsrc[it*256 + tid];
        // pair coefficients (2-sparse cosine basis)
        if (tid < 96){
            float dx = gAx[tid]-gBc[bb*3+0];
            float dy = gAy[tid]-gBc[bb*3+1];
            float dz = gAz[tid]-gBc[bb*3+2];
            float r = sqrtf(dx*dx+dy*dy+dz*dz);
            float u = r * 3.9f;                 // r/step, step=10/39
            int k0 = (int)u;
            float fr = u - (float)k0;
            float cs = __cosf(fr * 1.57079632679489662f);
            float c0 = cs*cs;
            float c1 = 1.f - c0;
            if (k0   >= NBAS) c0 = 0.f;
            if (k0+1 >= NBAS) c1 = 0.f;
            pc0[tid] = c0; pc1[tid] = c1;
            po0[tid] = min(k0, NBAS-1)*64;
            po1[tid] = min(k0+1, NBAS-1)*64;
        }
        __syncthreads();   // pairs ready; prev contraction done reading A1s/Bts
        // h1: lane=hin, wave w covers a = i*4+w
        #pragma unroll 8
        for (int i = 0; i < 24; i++){
            int a = (i<<2) + w;
            float c0 = pc0[a], c1 = pc1[a];
            int o0 = po0[a], o1 = po1[a];
            float pre = bias1 + c0*W1s[o0+lane] + c1*W1s[o1+lane];
            A1s[a*72 + lane] = f2bf(sspf(pre));
        }
        // commit B-tile to LDS
        #pragma unroll
        for (int it = 0; it < 4; it++){
            int c = it*256 + tid;
            *(uint4*)((char*)Bts + ((c>>3)*144 + (c&7)*16)) = breg[it];
        }
        __syncthreads();
        // h2 GEMM: R_pre = h1 @ rW2 (M=96,N=64,K=64), 24 tiles over 4 waves
        f32x4 hacc[6];
        #pragma unroll
        for (int t = 0; t < 6; t++){
            hacc[t] = (f32x4){0.f,0.f,0.f,0.f};
            int tt = w*6 + t;
            int mt = tt >> 2, nt = tt & 3;
            #pragma unroll
            for (int ks = 0; ks < 2; ks++){
                bf16x8 af = *(const bf16x8*)(A1s + (mt*16 + l15)*72 + ks*32 + q*8);
                bf16x8 bf_ = *(const bf16x8*)(w2T + (nt*16 + l15)*72 + ks*32 + q*8);
                hacc[t] = __builtin_amdgcn_mfma_f32_16x16x32_bf16(af, bf_, hacc[t], 0, 0, 0);
            }
        }
        __syncthreads();   // all h1 reads done -> safe to overwrite A1s with R
        #pragma unroll
        for (int t = 0; t < 6; t++){
            int tt = w*6 + t;
            int mt = tt >> 2, nt = tt & 3;
            float b2 = rb2s[nt*16 + l15];
            #pragma unroll
            for (int e = 0; e < 4; e++){
                int a = mt*16 + q*4 + e;
                A1s[a*72 + nt*16 + l15] = f2bf(sspf(hacc[t][e] + b2));
            }
        }
        __syncthreads();
        // contraction: C[96,128] += R[96,64] @ Bt[64,128]; wave = 48x64 region
        #pragma unroll
        for (int mt = 0; mt < 3; mt++){
            #pragma unroll
            for (int ks = 0; ks < 2; ks++){
                bf16x8 af = *(const bf16x8*)(A1s + (wm*48 + mt*16 + l15)*72 + ks*32 + q*8);
                #pragma unroll
                for (int nt = 0; nt < 4; nt++){
                    bf16x8 bf_ = *(const bf16x8*)(Bts + (wn*64 + nt*16 + l15)*72 + ks*32 + q*8);
                    acc4[mt*4+nt] = __builtin_amdgcn_mfma_f32_16x16x32_bf16(af, bf_, acc4[mt*4+nt], 0, 0, 0);
                }
            }
        }
    }
    // write partials
    size_t base = (size_t)(z*NCHUNK + chunk)*192*128;
    #pragma unroll
    for (int mt = 0; mt < 3; mt++){
        #pragma unroll
        for (int nt = 0; nt < 4; nt++){
            #pragma unroll
            for (int e = 0; e < 4; e++){
                int ag = a0 + wm*48 + mt*16 + q*4 + e;
                int j2 = wn*64 + nt*16 + l15;
                part[base + (size_t)ag*128 + j2] = acc4[mt*4+nt][e];
            }
        }
    }
}

// ---------------- reduce partials over chunks + sp + mask -> next features
__global__ void k_reduce(const float* __restrict__ part, const float* __restrict__ mask,
                         float* __restrict__ fb, float* __restrict__ fc){
    int idx = blockIdx.x*256 + threadIdx.x;      // 393216 total
    int row = idx >> 7;            // z*192 + a
    int j2 = idx & 127;
    int z = row / NATOMS;
    int a = row - z*NATOMS;
    const float* p = part + ((size_t)(z*NCHUNK)*192 + a)*128 + j2;
    float s = 0.f;
    #pragma unroll
    for (int c = 0; c < NCHUNK; c++) s += p[(size_t)c*192*128];
    float v = spf_act(s) * mask[row];
    if (j2 < 64) fb[row*64 + j2] = v;
    else         fc[row*64 + j2 - 64] = v;
}

// ---------------- head
__global__ void k_h1(const float* __restrict__ fbio, const float* __restrict__ fch,
                     const float* __restrict__ fW1, const float* __restrict__ fb1,
                     float* __restrict__ y1){
    __shared__ float xr[4][128];
    int r0 = blockIdx.x*4, tid = threadIdx.x;   // 128 threads
    for (int i = tid; i < 512; i += 128){
        int r = i >> 7, c = i & 127;
        int row = r0 + r;
        xr[r][c] = (c < 64) ? fbio[row*64 + c] : fch[row*64 + c - 64];
    }
    __syncthreads();
    int k = tid;
    float b = fb1[k];
    float a0 = b, a1 = b, a2 = b, a3 = b;
    #pragma unroll 8
    for (int c = 0; c < 128; c++){
        float w = fW1[c*128 + k];
        a0 += xr[0][c]*w; a1 += xr[1][c]*w; a2 += xr[2][c]*w; a3 += xr[3][c]*w;
    }
    y1[(r0+0)*128+k] = a0; y1[(r0+1)*128+k] = a1;
    y1[(r0+2)*128+k] = a2; y1[(r0+3)*128+k] = a3;
}

__global__ void k_bn1(float* __restrict__ y1){
    int a = blockIdx.x, tid = threadIdx.x;   // 256 threads, 2048 vals
    float v[8]; float s = 0.f, ss = 0.f;
    #pragma unroll
    for (int i = 0; i < 8; i++){
        int e = tid + i*256;
        int zz = e >> 7, k = e & 127;
        float x = y1[(zz*NATOMS + a)*128 + k];
        v[i] = x; s += x; ss += x*x;
    }
    for (int off = 32; off; off >>= 1){ s += __shfl_down(s, off); ss += __shfl_down(ss, off); }
    __shared__ float wsum[8]; __shared__ float stats[2];
    int lane = tid & 63, w = tid >> 6;
    if (!lane){ wsum[w] = s; wsum[4+w] = ss; }
    __syncthreads();
    if (!tid){
        float S = wsum[0]+wsum[1]+wsum[2]+wsum[3];
        float SS = wsum[4]+wsum[5]+wsum[6]+wsum[7];
        float m = S*(1.f/2048.f);
        float var = SS*(1.f/2048.f) - m*m;
        stats[0] = m; stats[1] = rsqrtf(var + 1e-5f);
    }
    __syncthreads();
    float m = stats[0], inv = stats[1];
    #pragma unroll
    for (int i = 0; i < 8; i++){
        int e = tid + i*256;
        int zz = e >> 7, k = e & 127;
        float x = (v[i]-m)*inv;
        x = (x > 0.f) ? x : 0.2f*x;
        y1[(zz*NATOMS + a)*128 + k] = x;
    }
}

__global__ void k_h2(const float* __restrict__ y1, const float* __restrict__ fW2,
                     const float* __restrict__ fb2, float* __restrict__ y2){
    __shared__ float xr[4][128];
    int r0 = blockIdx.x*4, tid = threadIdx.x;  // 128 threads
    for (int i = tid; i < 512; i += 128){ int r = i >> 7, c = i & 127; xr[r][c] = y1[(r0+r)*128 + c]; }
    __syncthreads();
    int jj = tid & 31, r = tid >> 5;
    float acc = fb2[jj];
    #pragma unroll 8
    for (int c = 0; c < 128; c++) acc += xr[r][c]*fW2[c*32 + jj];
    y2[(r0+r)*32 + jj] = acc;
}

__global__ void k_bn2(float* __restrict__ y2, const float* __restrict__ mask){
    int a = blockIdx.x, tid = threadIdx.x;   // 256 threads, 512 vals
    int e0 = tid, e1 = tid + 256;
    int z0 = e0 >> 5, j0 = e0 & 31, z1 = e1 >> 5, j1 = e1 & 31;
    float v0 = y2[(z0*NATOMS + a)*32 + j0];
    float v1 = y2[(z1*NATOMS + a)*32 + j1];
    float s = v0 + v1, ss = v0*v0 + v1*v1;
    for (int off = 32; off; off >>= 1){ s += __shfl_down(s, off); ss += __shfl_down(ss, off); }
    __shared__ float wsum[8]; __shared__ float stats[2];
    int lane = tid & 63, w = tid >> 6;
    if (!lane){ wsum[w] = s; wsum[4+w] = ss; }
    __syncthreads();
    if (!tid){
        float S = wsum[0]+wsum[1]+wsum[2]+wsum[3];
        float SS = wsum[4]+wsum[5]+wsum[6]+wsum[7];
        float m = S*(1.f/512.f);
        float var = SS*(1.f/512.f) - m*m;
        stats[0] = m; stats[1] = rsqrtf(var + 1e-5f);
    }
    __syncthreads();
    float m = stats[0], inv = stats[1];
    float x0 = (v0-m)*inv; x0 = (x0 > 0.f) ? x0 : 0.2f*x0; x0 *= mask[z0*NATOMS + a];
    float x1 = (v1-m)*inv; x1 = (x1 > 0.f) ? x1 : 0.2f*x1; x1 *= mask[z1*NATOMS + a];
    y2[(z0*NATOMS + a)*32 + j0] = x0;
    y2[(z1*NATOMS + a)*32 + j1] = x1;
}

__global__ void k_sum(const float* __restrict__ y2, float* __restrict__ out){
    int e = blockIdx.x;           // 512 outputs
    int z = e >> 5, jj = e & 31;
    int tid = threadIdx.x;        // 64
    float s = 0.f;
    for (int a = tid; a < NATOMS; a += 64) s += y2[(z*NATOMS + a)*32 + jj];
    for (int off = 32; off; off >>= 1) s += __shfl_down(s, off);
    if (!tid) out[e] = s;
}

extern "C" void kernel_launch(void* const* d_in, const int* in_sizes, int n_in,
                              void* d_out, int out_size, void* d_ws, size_t ws_size,
                              hipStream_t stream){
    const float* features = (const float*)d_in[0];
    const float* geometry = (const float*)d_in[1];
    const float* mask     = (const float*)d_in[2];
    const float* W_bio    = (const float*)d_in[3];
    const float* b_bio    = (const float*)d_in[4];
    const float* W_ch     = (const float*)d_in[5];
    const float* b_ch     = (const float*)d_in[6];
    const float* rW1[2] = {(const float*)d_in[7],  (const float*)d_in[12]};
    const float* rb1[2] = {(const float*)d_in[8],  (const float*)d_in[13]};
    const float* rW2[2] = {(const float*)d_in[9],  (const float*)d_in[14]};
    const float* rb2[2] = {(const float*)d_in[10], (const float*)d_in[15]};
    const float* rWo[2] = {(const float*)d_in[11], (const float*)d_in[16]};
    const float* fW1 = (const float*)d_in[17];
    const float* fb1 = (const float*)d_in[18];
    const float* fW2 = (const float*)d_in[19];
    const float* fb2 = (const float*)d_in[20];

    char* ws = (char*)d_ws;
    float* f0b = (float*)ws;                         ws += (size_t)ZA*64*4;
    float* f0c = (float*)ws;                         ws += (size_t)ZA*64*4;
    float* f1b = (float*)ws;                         ws += (size_t)ZA*64*4;
    float* f1c = (float*)ws;                         ws += (size_t)ZA*64*4;
    unsigned short* tmpT = (unsigned short*)ws;      ws += (size_t)ZA*128*64*2;   // 50.3 MB
    float* part = (float*)ws;                        ws += (size_t)ZB*NCHUNK*192*128*4; // 25.2 MB
    float* y1 = (float*)ws;                          ws += (size_t)ZA*128*4;
    float* y2 = (float*)ws;                          ws += (size_t)ZA*32*4;

    k_encode<<<ZA, 64, 0, stream>>>(features, W_bio, b_bio, W_ch, b_ch, f0b, f0c);

    dim3 gt(96, 64);
    dim3 gc(ZB, NCHUNK, 2);
    // layer 0
    k_tmp<<<gt, 256, 0, stream>>>(f0b, f0c, mask, rWo[0], tmpT);
    k_conv<<<gc, 256, 0, stream>>>(geometry, rW1[0], rb1[0], rW2[0], rb2[0], tmpT, part);
    k_reduce<<<1536, 256, 0, stream>>>(part, mask, f1b, f1c);
    // layer 1
    k_tmp<<<gt, 256, 0, stream>>>(f1b, f1c, mask, rWo[1], tmpT);
    k_conv<<<gc, 256, 0, stream>>>(geometry, rW1[1], rb1[1], rW2[1], rb2[1], tmpT, part);
    k_reduce<<<1536, 256, 0, stream>>>(part, mask, f0b, f0c);
    // head
    k_h1<<<ZA/4, 128, 0, stream>>>(f0b, f0c, fW1, fb1, y1);
    k_bn1<<<NATOMS, 256, 0, stream>>>(y1);
    k_h2<<<ZA/4, 128, 0, stream>>>(y1, fW2, fb2, y2);
    k_bn2<<<NATOMS, 256, 0, stream>>>(y2, mask);
    k_sum<<<512, 64, 0, stream>>>(y2, (float*)d_out);
}

// Round 4
// 376.718 us; speedup vs baseline: 6.9278x; 1.2184x over previous
//
#include <hip/hip_runtime.h>
#include <math.h>

#define ZB 16
#define NATOMS 192
#define NBAS 40
#define ZA (ZB*NATOMS)       // 3072
#define ZCH 8                // z per chunk
#define NKC 32               // K-chunks per contract block-column

typedef __attribute__((ext_vector_type(4))) float f32x4;
typedef __attribute__((ext_vector_type(8))) short bf16x8;

__device__ __forceinline__ unsigned short f2bf(float x){
    union { float f; unsigned u; } v; v.f = x;
    unsigned r = v.u + 0x7FFFu + ((v.u >> 16) & 1u);
    return (unsigned short)(r >> 16);
}
__device__ __forceinline__ float bf2f(unsigned short u){
    union { unsigned u; float f; } v; v.u = ((unsigned)u) << 16; return v.f;
}
// ssp(x) = softplus(5x)/5 - ln2/5 via hw exp2/log2
__device__ __forceinline__ float sspf(float x){
    float t = 7.2134752f*x;
    float tc = fminf(t, 126.f);
    float e = __builtin_amdgcn_exp2f(tc);
    float l = __builtin_amdgcn_logf(1.f + e);   // log2
    float r = fmaf(l, 0.13862944f, -0.13862944f);
    return (t > 126.f) ? (x - 0.13862944f) : r;
}
__device__ __forceinline__ float spf_act(float x){
    float t = 7.2134752f*x;
    float tc = fminf(t, 126.f);
    float e = __builtin_amdgcn_exp2f(tc);
    float l = __builtin_amdgcn_logf(1.f + e);
    float r = l*0.13862944f;
    return (t > 126.f) ? x : r;
}

// ---------------- encoders -> bf16 features
__global__ void k_encode(const float* __restrict__ feat, const float* __restrict__ Wb,
                         const float* __restrict__ bb, const float* __restrict__ Wc,
                         const float* __restrict__ bc, unsigned short* __restrict__ fbio,
                         unsigned short* __restrict__ fch){
    int za = blockIdx.x; int e = threadIdx.x;      // 64 threads
    const float* fr = feat + za*8;
    float accb = bb[e];
    #pragma unroll
    for (int c = 0; c < 7; c++) accb += fr[c]*Wb[c*64+e];
    float accc = bc[e] + fr[7]*Wc[e];
    fbio[za*64+e] = f2bf(accb);
    fch[za*64+e]  = f2bf(accc);
}

// ---------------- prep: Bp[(j*64+h)][i] = rWo[h][j][i] bf16 ; w2b[hout][hin] = rW2[hin][hout] bf16
__global__ void k_prep(const float* __restrict__ rWo, const float* __restrict__ rW2,
                       unsigned short* __restrict__ Bp, unsigned short* __restrict__ w2b){
    int tid = threadIdx.x;
    if (blockIdx.x < 1024){
        int idx = blockIdx.x*256 + tid;          // [0, 262144)
        int n = idx >> 6, i = idx & 63;
        int j = n >> 6, h = n & 63;
        Bp[idx] = f2bf(rWo[(h*64 + j)*64 + i]);
    } else {
        int idx = (blockIdx.x - 1024)*256 + tid; // [0, 4096)
        int hout = idx >> 6, hin = idx & 63;
        w2b[idx] = f2bf(rW2[hin*64 + hout]);
    }
}

// ---------------- tmp GEMM bf16 MFMA: out[m][(j,h)] = sum_i f_s[m][i]*Bp[(j,h)][i],
// epilogue *mask*c, written to Tg[m_loc*8192 + s*4096 + n]
__global__ __launch_bounds__(256,2) void k_tmpB(
    const unsigned short* __restrict__ fb, const unsigned short* __restrict__ fc,
    const float* __restrict__ mask, const unsigned short* __restrict__ Bp,
    unsigned short* __restrict__ Tg, int moff)
{
    __shared__ unsigned short sm[18432];   // As[128*72] | Bs[128*72]; Cs overlays all
    __shared__ float msk[128];
    unsigned short* As = sm;
    unsigned short* Bs = sm + 9216;
    unsigned short* Cs = sm;

    int tid = threadIdx.x;
    int m0l = blockIdx.x*128, n0 = blockIdx.y*128, s = blockIdx.z;
    int m0g = moff + m0l;
    int lane = tid & 63, w = tid >> 6, q = lane >> 4, l15 = lane & 15;
    int wm = w & 1, wn = w >> 1;

    const unsigned short* f = s ? fc : fb;
    #pragma unroll
    for (int it = 0; it < 4; it++){
        int idx = tid + it*256;                // 1024 uint4
        int r = idx >> 3, c8 = idx & 7;
        *(uint4*)(As + r*72 + c8*8) = *(const uint4*)(f + (size_t)(m0g + r)*64 + c8*8);
    }
    #pragma unroll
    for (int it = 0; it < 4; it++){
        int idx = tid + it*256;
        int r = idx >> 3, c8 = idx & 7;
        *(uint4*)(Bs + r*72 + c8*8) = *(const uint4*)(Bp + (size_t)(n0 + r)*64 + c8*8);
    }
    if (tid < 128) msk[tid] = mask[m0g + tid] * 0.07216878364870322f;
    __syncthreads();

    f32x4 acc[16];
    #pragma unroll
    for (int i = 0; i < 16; i++) acc[i] = (f32x4){0.f,0.f,0.f,0.f};
    #pragma unroll
    for (int kc = 0; kc < 2; kc++){
        bf16x8 af[4];
        #pragma unroll
        for (int mt = 0; mt < 4; mt++)
            af[mt] = *(const bf16x8*)(As + (wm*64 + mt*16 + l15)*72 + kc*32 + q*8);
        #pragma unroll
        for (int nt = 0; nt < 4; nt++){
            bf16x8 bf_ = *(const bf16x8*)(Bs + (wn*64 + nt*16 + l15)*72 + kc*32 + q*8);
            #pragma unroll
            for (int mt = 0; mt < 4; mt++)
                acc[mt*4+nt] = __builtin_amdgcn_mfma_f32_16x16x32_bf16(af[mt], bf_, acc[mt*4+nt], 0, 0, 0);
        }
    }
    __syncthreads();   // all As/Bs reads done -> overlay Cs
    #pragma unroll
    for (int mt = 0; mt < 4; mt++)
        #pragma unroll
        for (int nt = 0; nt < 4; nt++)
            #pragma unroll
            for (int e = 0; e < 4; e++){
                int row2 = mt*16 + q*4 + e;
                float v = acc[mt*4+nt][e] * msk[wm*64 + row2];
                Cs[w*4608 + row2*72 + nt*16 + l15] = f2bf(v);
            }
    __syncthreads();
    #pragma unroll
    for (int it = 0; it < 8; it++){
        int flat = lane + it*64;               // [0,512)
        int rr = flat >> 3, c8 = flat & 7;
        uint4 v = *(const uint4*)(Cs + w*4608 + rr*72 + c8*8);
        size_t dst = (size_t)(m0l + wm*64 + rr)*8192 + s*4096 + n0 + wn*64 + c8*8;
        *(uint4*)(Tg + dst) = v;
    }
}

// ---------------- radial MLP -> R[zl][a][b][h] bf16 (16x16 pair tile per block)
__global__ __launch_bounds__(256,2) void k_radial(
    const float* __restrict__ geom,
    const float* __restrict__ rW1, const float* __restrict__ rb1,
    const unsigned short* __restrict__ w2b, const float* __restrict__ rb2,
    unsigned short* __restrict__ Rc, int zoff)
{
    __shared__ unsigned short H[256*72];      // h1, then R tile
    __shared__ unsigned short Wt[64*72];
    __shared__ float W1s[NBAS*64];
    __shared__ float rb1s[64], rb2s[64];
    __shared__ float pc0s[256], pc1s[256];
    __shared__ int po0s[256], po1s[256];
    __shared__ float gx[16],gy[16],gz[16],hx[16],hy[16],hz[16];

    int tid = threadIdx.x;
    int zl = blockIdx.x;
    int z = zoff + zl;
    int ta = blockIdx.y % 12, tb = blockIdx.y / 12;
    int a0 = ta*16, b0 = tb*16;
    int lane = tid & 63, w = tid >> 6, q = lane >> 4, l15 = lane & 15;

    #pragma unroll
    for (int i = 0; i < 10; i++) W1s[tid + i*256] = rW1[tid + i*256];
    #pragma unroll
    for (int it = 0; it < 2; it++){
        int e = tid + it*256;                 // [0,512)
        int row = e >> 3, c8 = e & 7;
        *(uint4*)(Wt + row*72 + c8*8) = *(const uint4*)(w2b + row*64 + c8*8);
    }
    if (tid < 64){ rb1s[tid] = rb1[tid]; rb2s[tid] = rb2[tid]; }
    if (tid < 16){
        int g = (z*NATOMS + a0 + tid)*3;
        gx[tid] = geom[g]; gy[tid] = geom[g+1]; gz[tid] = geom[g+2];
    } else if (tid < 32){
        int t2 = tid - 16;
        int g = (z*NATOMS + b0 + t2)*3;
        hx[t2] = geom[g]; hy[t2] = geom[g+1]; hz[t2] = geom[g+2];
    }
    __syncthreads();

    {   // pair coefficients
        int a_l = tid >> 4, b_l = tid & 15;
        float dx = gx[a_l]-hx[b_l], dy = gy[a_l]-hy[b_l], dz = gz[a_l]-hz[b_l];
        float r = sqrtf(dx*dx + dy*dy + dz*dz);
        float u = r * 3.9f;
        int k0 = (int)u;
        float fr = u - (float)k0;
        float cs = __cosf(fr * 1.57079632679489662f);
        float c0 = cs*cs, c1 = 1.f - c0;
        if (k0   >= NBAS) c0 = 0.f;
        if (k0+1 >= NBAS) c1 = 0.f;
        pc0s[tid] = c0; pc1s[tid] = c1;
        po0s[tid] = min(k0, NBAS-1)*64;
        po1s[tid] = min(k0+1, NBAS-1)*64;
    }
    __syncthreads();

    float bias1 = rb1s[lane];
    #pragma unroll 8
    for (int i = 0; i < 64; i++){
        int p = w*64 + i;
        float c0 = pc0s[p], c1 = pc1s[p];
        int o0 = po0s[p], o1 = po1s[p];
        float pre = bias1 + c0*W1s[o0 + lane] + c1*W1s[o1 + lane];
        H[p*72 + lane] = f2bf(sspf(pre));
    }
    __syncthreads();

    f32x4 acc[16];
    #pragma unroll
    for (int i = 0; i < 16; i++) acc[i] = (f32x4){0.f,0.f,0.f,0.f};
    #pragma unroll
    for (int kc = 0; kc < 2; kc++){
        bf16x8 af[4];
        #pragma unroll
        for (int mt = 0; mt < 4; mt++)
            af[mt] = *(const bf16x8*)(H + ((w*4 + mt)*16 + l15)*72 + kc*32 + q*8);
        #pragma unroll
        for (int nt = 0; nt < 4; nt++){
            bf16x8 bf_ = *(const bf16x8*)(Wt + (nt*16 + l15)*72 + kc*32 + q*8);
            #pragma unroll
            for (int mt = 0; mt < 4; mt++)
                acc[mt*4+nt] = __builtin_amdgcn_mfma_f32_16x16x32_bf16(af[mt], bf_, acc[mt*4+nt], 0, 0, 0);
        }
    }
    __syncthreads();
    #pragma unroll
    for (int mt = 0; mt < 4; mt++)
        #pragma unroll
        for (int nt = 0; nt < 4; nt++){
            float b2 = rb2s[nt*16 + l15];
            #pragma unroll
            for (int e = 0; e < 4; e++){
                int p = (w*4 + mt)*16 + q*4 + e;
                H[p*72 + nt*16 + l15] = f2bf(sspf(acc[mt*4+nt][e] + b2));
            }
        }
    __syncthreads();
    // copy R tile out: R[zl][a0+a_l][b0+b_l][h]
    #pragma unroll
    for (int it = 0; it < 8; it++){
        int e = tid + it*256;                  // [0,2048) uint4s
        int a_l = e >> 7, b_l = (e >> 3) & 15, h0 = (e & 7)*8;
        uint4 v = *(const uint4*)(H + (a_l*16 + b_l)*72 + h0);
        size_t dst = ((size_t)(zl*NATOMS + a0 + a_l)*NATOMS + b0 + b_l)*64 + h0;
        *(uint4*)(Rc + dst) = v;
    }
}

// ---------------- contraction: part[zl][kc][a][j2] = sum_{k in chunk} R[a][k]*T[k][j2]
__global__ __launch_bounds__(256,2) void k_contract(
    const unsigned short* __restrict__ Rc, const unsigned short* __restrict__ Tc,
    float* __restrict__ part)
{
    __shared__ unsigned short sm[2*6912 + 2*4608];
    // layout: A buf0 [0,6912) | A buf1 [6912,13824) | B buf0 [13824,18432) | B buf1 [18432,23040)

    int tid = threadIdx.x;
    int zl = blockIdx.x, kc = blockIdx.y;
    int lane = tid & 63, w = tid >> 6, q = lane >> 4, l15 = lane & 15;

    f32x4 acc[24];
    #pragma unroll
    for (int i = 0; i < 24; i++) acc[i] = (f32x4){0.f,0.f,0.f,0.f};

    const size_t Rbase = (size_t)zl*NATOMS*12288;
    const size_t Tbase = (size_t)zl*NATOMS*8192;

    #define STAGE(BUF, KS) { \
        int aoff_ = (BUF)*6912; int boff_ = 13824 + (BUF)*4608; \
        int b_ = kc*6 + ((KS) >> 1); int h0_ = ((KS) & 1)*32; \
        const unsigned short* Ab = Rc + Rbase + (size_t)b_*64 + h0_; \
        _Pragma("unroll") \
        for (int r_ = 0; r_ < 3; r_++){ \
            int idx = tid + r_*256; int a_ = idx >> 2, c8_ = idx & 3; \
            *(uint4*)(sm + aoff_ + a_*36 + c8_*8) = *(const uint4*)(Ab + (size_t)a_*12288 + c8_*8); \
        } \
        const unsigned short* Bb = Tc + Tbase + (size_t)b_*8192 + h0_; \
        _Pragma("unroll") \
        for (int r_ = 0; r_ < 2; r_++){ \
            int idx = tid + r_*256; int j_ = idx >> 2, c8_ = idx & 3; \
            *(uint4*)(sm + boff_ + j_*36 + c8_*8) = *(const uint4*)(Bb + (size_t)j_*64 + c8_*8); \
        } }

    STAGE(0, 0)
    __syncthreads();
    for (int ks = 0; ks < 12; ks++){
        int buf = ks & 1;
        if (ks < 11) STAGE(buf^1, ks+1)
        int aoff = buf*6912, boff = 13824 + buf*4608;
        bf16x8 af[3];
        #pragma unroll
        for (int mt = 0; mt < 3; mt++)
            af[mt] = *(const bf16x8*)(sm + aoff + (w*48 + mt*16 + l15)*36 + q*8);
        #pragma unroll
        for (int nt = 0; nt < 8; nt++){
            bf16x8 bf_ = *(const bf16x8*)(sm + boff + (nt*16 + l15)*36 + q*8);
            #pragma unroll
            for (int mt = 0; mt < 3; mt++)
                acc[mt*8+nt] = __builtin_amdgcn_mfma_f32_16x16x32_bf16(af[mt], bf_, acc[mt*8+nt], 0, 0, 0);
        }
        __syncthreads();
    }
    float* pbase = part + ((size_t)(zl*NKC + kc)*NATOMS)*128;
    #pragma unroll
    for (int mt = 0; mt < 3; mt++)
        #pragma unroll
        for (int nt = 0; nt < 8; nt++)
            #pragma unroll
            for (int e = 0; e < 4; e++){
                int a = w*48 + mt*16 + q*4 + e;
                int j2 = nt*16 + l15;
                pbase[a*128 + j2] = acc[mt*8+nt][e];
            }
    #undef STAGE
}

// ---------------- reduce partials + sp + mask -> bf16 next features
__global__ void k_reduceB(const float* __restrict__ part, const float* __restrict__ mask,
                          unsigned short* __restrict__ fb, unsigned short* __restrict__ fc,
                          int zoff){
    int zl = blockIdx.y;
    int idx = blockIdx.x*256 + threadIdx.x;    // [0, 24576)
    int a = idx >> 7, j2 = idx & 127;
    const float* p = part + ((size_t)(zl*NKC)*NATOMS + a)*128 + j2;
    float s = 0.f;
    #pragma unroll
    for (int c = 0; c < NKC; c++) s += p[(size_t)c*NATOMS*128];
    int rowg = (zoff + zl)*NATOMS + a;
    float v = spf_act(s) * mask[rowg];
    if (j2 < 64) fb[rowg*64 + j2] = f2bf(v);
    else         fc[rowg*64 + j2 - 64] = f2bf(v);
}

// ---------------- head
__global__ void k_h1(const unsigned short* __restrict__ fbio, const unsigned short* __restrict__ fch,
                     const float* __restrict__ fW1, const float* __restrict__ fb1,
                     float* __restrict__ y1){
    __shared__ float xr[4][128];
    int r0 = blockIdx.x*4, tid = threadIdx.x;   // 128 threads
    for (int i = tid; i < 512; i += 128){
        int r = i >> 7, c = i & 127;
        int row = r0 + r;
        xr[r][c] = (c < 64) ? bf2f(fbio[row*64 + c]) : bf2f(fch[row*64 + c - 64]);
    }
    __syncthreads();
    int k = tid;
    float b = fb1[k];
    float a0 = b, a1 = b, a2 = b, a3 = b;
    #pragma unroll 8
    for (int c = 0; c < 128; c++){
        float w = fW1[c*128 + k];
        a0 += xr[0][c]*w; a1 += xr[1][c]*w; a2 += xr[2][c]*w; a3 += xr[3][c]*w;
    }
    y1[(r0+0)*128+k] = a0; y1[(r0+1)*128+k] = a1;
    y1[(r0+2)*128+k] = a2; y1[(r0+3)*128+k] = a3;
}

__global__ void k_bn1(float* __restrict__ y1){
    int a = blockIdx.x, tid = threadIdx.x;   // 256 threads, 2048 vals
    float v[8]; float s = 0.f, ss = 0.f;
    #pragma unroll
    for (int i = 0; i < 8; i++){
        int e = tid + i*256;
        int zz = e >> 7, k = e & 127;
        float x = y1[(zz*NATOMS + a)*128 + k];
        v[i] = x; s += x; ss += x*x;
    }
    for (int off = 32; off; off >>= 1){ s += __shfl_down(s, off); ss += __shfl_down(ss, off); }
    __shared__ float wsum[8]; __shared__ float stats[2];
    int lane = tid & 63, w = tid >> 6;
    if (!lane){ wsum[w] = s; wsum[4+w] = ss; }
    __syncthreads();
    if (!tid){
        float S = wsum[0]+wsum[1]+wsum[2]+wsum[3];
        float SS = wsum[4]+wsum[5]+wsum[6]+wsum[7];
        float m = S*(1.f/2048.f);
        float var = SS*(1.f/2048.f) - m*m;
        stats[0] = m; stats[1] = rsqrtf(var + 1e-5f);
    }
    __syncthreads();
    float m = stats[0], inv = stats[1];
    #pragma unroll
    for (int i = 0; i < 8; i++){
        int e = tid + i*256;
        int zz = e >> 7, k = e & 127;
        float x = (v[i]-m)*inv;
        x = (x > 0.f) ? x : 0.2f*x;
        y1[(zz*NATOMS + a)*128 + k] = x;
    }
}

__global__ void k_h2(const float* __restrict__ y1, const float* __restrict__ fW2,
                     const float* __restrict__ fb2, float* __restrict__ y2){
    __shared__ float xr[4][128];
    int r0 = blockIdx.x*4, tid = threadIdx.x;  // 128 threads
    for (int i = tid; i < 512; i += 128){ int r = i >> 7, c = i & 127; xr[r][c] = y1[(r0+r)*128 + c]; }
    __syncthreads();
    int jj = tid & 31, r = tid >> 5;
    float acc = fb2[jj];
    #pragma unroll 8
    for (int c = 0; c < 128; c++) acc += xr[r][c]*fW2[c*32 + jj];
    y2[(r0+r)*32 + jj] = acc;
}

__global__ void k_bn2(float* __restrict__ y2, const float* __restrict__ mask){
    int a = blockIdx.x, tid = threadIdx.x;   // 256 threads, 512 vals
    int e0 = tid, e1 = tid + 256;
    int z0 = e0 >> 5, j0 = e0 & 31, z1 = e1 >> 5, j1 = e1 & 31;
    float v0 = y2[(z0*NATOMS + a)*32 + j0];
    float v1 = y2[(z1*NATOMS + a)*32 + j1];
    float s = v0 + v1, ss = v0*v0 + v1*v1;
    for (int off = 32; off; off >>= 1){ s += __shfl_down(s, off); ss += __shfl_down(ss, off); }
    __shared__ float wsum[8]; __shared__ float stats[2];
    int lane = tid & 63, w = tid >> 6;
    if (!lane){ wsum[w] = s; wsum[4+w] = ss; }
    __syncthreads();
    if (!tid){
        float S = wsum[0]+wsum[1]+wsum[2]+wsum[3];
        float SS = wsum[4]+wsum[5]+wsum[6]+wsum[7];
        float m = S*(1.f/512.f);
        float var = SS*(1.f/512.f) - m*m;
        stats[0] = m; stats[1] = rsqrtf(var + 1e-5f);
    }
    __syncthreads();
    float m = stats[0], inv = stats[1];
    float x0 = (v0-m)*inv; x0 = (x0 > 0.f) ? x0 : 0.2f*x0; x0 *= mask[z0*NATOMS + a];
    float x1 = (v1-m)*inv; x1 = (x1 > 0.f) ? x1 : 0.2f*x1; x1 *= mask[z1*NATOMS + a];
    y2[(z0*NATOMS + a)*32 + j0] = x0;
    y2[(z1*NATOMS + a)*32 + j1] = x1;
}

__global__ void k_sum(const float* __restrict__ y2, float* __restrict__ out){
    int e = blockIdx.x;           // 512 outputs
    int z = e >> 5, jj = e & 31;
    int tid = threadIdx.x;        // 64
    float s = 0.f;
    for (int a = tid; a < NATOMS; a += 64) s += y2[(z*NATOMS + a)*32 + jj];
    for (int off = 32; off; off >>= 1) s += __shfl_down(s, off);
    if (!tid) out[e] = s;
}

extern "C" void kernel_launch(void* const* d_in, const int* in_sizes, int n_in,
                              void* d_out, int out_size, void* d_ws, size_t ws_size,
                              hipStream_t stream){
    const float* features = (const float*)d_in[0];
    const float* geometry = (const float*)d_in[1];
    const float* mask     = (const float*)d_in[2];
    const float* W_bio    = (const float*)d_in[3];
    const float* b_bio    = (const float*)d_in[4];
    const float* W_ch     = (const float*)d_in[5];
    const float* b_ch     = (const float*)d_in[6];
    const float* rW1[2] = {(const float*)d_in[7],  (const float*)d_in[12]};
    const float* rb1[2] = {(const float*)d_in[8],  (const float*)d_in[13]};
    const float* rW2[2] = {(const float*)d_in[9],  (const float*)d_in[14]};
    const float* rb2[2] = {(const float*)d_in[10], (const float*)d_in[15]};
    const float* rWo[2] = {(const float*)d_in[11], (const float*)d_in[16]};
    const float* fW1 = (const float*)d_in[17];
    const float* fb1 = (const float*)d_in[18];
    const float* fW2 = (const float*)d_in[19];
    const float* fb2 = (const float*)d_in[20];

    char* ws = (char*)d_ws;
    unsigned short* fb0 = (unsigned short*)ws;   ws += (size_t)ZA*64*2;
    unsigned short* fc0 = (unsigned short*)ws;   ws += (size_t)ZA*64*2;
    unsigned short* fb1_ = (unsigned short*)ws;  ws += (size_t)ZA*64*2;
    unsigned short* fc1_ = (unsigned short*)ws;  ws += (size_t)ZA*64*2;
    unsigned short* Bp = (unsigned short*)ws;    ws += (size_t)262144*2;
    unsigned short* w2b = (unsigned short*)ws;   ws += (size_t)4096*2;
    unsigned short* Tg = (unsigned short*)ws;    ws += (size_t)ZCH*NATOMS*128*64*2;   // 25.2 MB
    unsigned short* Rc = (unsigned short*)ws;    ws += (size_t)ZCH*NATOMS*NATOMS*64*2; // 37.7 MB
    float* part = (float*)ws;                    ws += (size_t)ZCH*NKC*NATOMS*128*4;   // 25.2 MB
    float* y1 = (float*)ws;                      ws += (size_t)ZA*128*4;
    float* y2 = (float*)ws;                      ws += (size_t)ZA*32*4;

    k_encode<<<ZA, 64, 0, stream>>>(features, W_bio, b_bio, W_ch, b_ch, fb0, fc0);

    const unsigned short* fin_b = fb0; const unsigned short* fin_c = fc0;
    unsigned short* fout_b = fb1_; unsigned short* fout_c = fc1_;
    for (int l = 0; l < 2; l++){
        k_prep<<<1040, 256, 0, stream>>>(rWo[l], rW2[l], Bp, w2b);
        for (int c = 0; c < 2; c++){
            int zoff = c*ZCH;
            int moff = zoff*NATOMS;
            dim3 gt(12, 32, 2);
            k_tmpB<<<gt, 256, 0, stream>>>(fin_b, fin_c, mask, Bp, Tg, moff);
            dim3 gr(ZCH, 144);
            k_radial<<<gr, 256, 0, stream>>>(geometry, rW1[l], rb1[l], w2b, rb2[l], Rc, zoff);
            dim3 gc(ZCH, NKC);
            k_contract<<<gc, 256, 0, stream>>>(Rc, Tg, part);
            dim3 gd(96, ZCH);
            k_reduceB<<<gd, 256, 0, stream>>>(part, mask, fout_b, fout_c, zoff);
        }
        // swap
        const unsigned short* tb = fin_b; const unsigned short* tc = fin_c;
        fin_b = fout_b; fin_c = fout_c;
        fout_b = (unsigned short*)tb; fout_c = (unsigned short*)tc;
    }
    // head (fin_* holds final features)
    k_h1<<<ZA/4, 128, 0, stream>>>(fin_b, fin_c, fW1, fb1, y1);
    k_bn1<<<NATOMS, 256, 0, stream>>>(y1);
    k_h2<<<ZA/4, 128, 0, stream>>>(y1, fW2, fb2, y2);
    k_bn2<<<NATOMS, 256, 0, stream>>>(y2, mask);
    k_sum<<<512, 64, 0, stream>>>(y2, (float*)d_out);
}

// Round 6
// 324.120 us; speedup vs baseline: 8.0521x; 1.1623x over previous
//
#include <hip/hip_runtime.h>
#include <math.h>

#define ZB 16
#define NATOMS 192
#define NBAS 40
#define ZA (ZB*NATOMS)       // 3072
#define NKC 32               // K-chunks in contraction

typedef __attribute__((ext_vector_type(4))) float f32x4;
typedef __attribute__((ext_vector_type(8))) short bf16x8;

__device__ __forceinline__ unsigned short f2bf(float x){
    union { float f; unsigned u; } v; v.f = x;
    unsigned r = v.u + 0x7FFFu + ((v.u >> 16) & 1u);
    return (unsigned short)(r >> 16);
}
__device__ __forceinline__ float bf2f(unsigned short u){
    union { unsigned u; float f; } v; v.u = ((unsigned)u) << 16; return v.f;
}
// ssp(x) = softplus(5x)/5 - ln2/5 via hw exp2/log2
__device__ __forceinline__ float sspf(float x){
    float t = 7.2134752f*x;
    float tc = fminf(t, 126.f);
    float e = __builtin_amdgcn_exp2f(tc);
    float l = __builtin_amdgcn_logf(1.f + e);   // log2
    float r = fmaf(l, 0.13862944f, -0.13862944f);
    return (t > 126.f) ? (x - 0.13862944f) : r;
}
__device__ __forceinline__ float spf_act(float x){
    float t = 7.2134752f*x;
    float tc = fminf(t, 126.f);
    float e = __builtin_amdgcn_exp2f(tc);
    float l = __builtin_amdgcn_logf(1.f + e);
    float r = l*0.13862944f;
    return (t > 126.f) ? x : r;
}

// ---------------- tmp GEMM bf16 MFMA: Tg[m][s*4096 + j*64 + h] = (f_s[m] @ rWo[h][j][:]) * mask*c
// layer 0 (feat != null): f_s rows computed on the fly from the linear encoders.
__global__ __launch_bounds__(256,2) void k_tmpB(
    const unsigned short* __restrict__ fb, const unsigned short* __restrict__ fc,
    const float* __restrict__ feat,
    const float* __restrict__ Wb, const float* __restrict__ bb,
    const float* __restrict__ Wc, const float* __restrict__ bc,
    const float* __restrict__ mask, const float* __restrict__ rWo,
    unsigned short* __restrict__ Tg)
{
    __shared__ unsigned short sm[18432];   // As[128*72] | Bs[128*72]; Cs overlays all
    __shared__ float msk[128];
    __shared__ float featS[128*8];
    __shared__ float WbS[7*64];
    __shared__ float bbS[64], WcS[64], bcS[64];
    unsigned short* As = sm;
    unsigned short* Bs = sm + 9216;
    unsigned short* Cs = sm;

    int tid = threadIdx.x;
    int m0 = blockIdx.x*128, n0 = blockIdx.y*128, s = blockIdx.z;
    int lane = tid & 63, w = tid >> 6, q = lane >> 4, l15 = lane & 15;
    int wm = w & 1, wn = w >> 1;

    if (feat){
        // stage encoder inputs
        #pragma unroll
        for (int it = 0; it < 4; it++){
            int idx = tid + it*256;            // 1024 floats
            featS[idx] = feat[(size_t)m0*8 + idx];
        }
        for (int i = tid; i < 448; i += 256) WbS[i] = Wb[i];   // 7x64, strided (256-thread block!)
        if (tid < 64){ bbS[tid] = bb[tid]; WcS[tid] = Wc[tid]; bcS[tid] = bc[tid]; }
        __syncthreads();
        #pragma unroll
        for (int it = 0; it < 32; it++){
            int idx = tid + it*256;            // 8192
            int r = idx >> 6, e = idx & 63;
            float acc;
            if (s == 0){
                acc = bbS[e];
                #pragma unroll
                for (int c = 0; c < 7; c++) acc += featS[r*8+c]*WbS[c*64+e];
            } else {
                acc = bcS[e] + featS[r*8+7]*WcS[e];
            }
            As[r*72 + e] = f2bf(acc);
        }
    } else {
        const unsigned short* f = s ? fc : fb;
        #pragma unroll
        for (int it = 0; it < 4; it++){
            int idx = tid + it*256;            // 1024 uint4
            int r = idx >> 3, c8 = idx & 7;
            *(uint4*)(As + r*72 + c8*8) = *(const uint4*)(f + (size_t)(m0 + r)*64 + c8*8);
        }
    }
    // B-staging: row r -> n = n0+r = j*64+h -> rWo[(h*64+j)*64 + i], fp32->bf16
    #pragma unroll
    for (int it = 0; it < 8; it++){
        int idx = tid + it*256;                // 2048 float4
        int r = idx >> 4, c4 = idx & 15;
        int n = n0 + r;
        int j = n >> 6, h = n & 63;
        float4 v = *(const float4*)(rWo + (size_t)(h*64 + j)*64 + c4*4);
        ushort4 o; o.x = f2bf(v.x); o.y = f2bf(v.y); o.z = f2bf(v.z); o.w = f2bf(v.w);
        *(ushort4*)(Bs + r*72 + c4*4) = o;
    }
    if (tid < 128) msk[tid] = mask[m0 + tid] * 0.07216878364870322f;
    __syncthreads();

    f32x4 acc[16];
    #pragma unroll
    for (int i = 0; i < 16; i++) acc[i] = (f32x4){0.f,0.f,0.f,0.f};
    #pragma unroll
    for (int kc = 0; kc < 2; kc++){
        bf16x8 af[4];
        #pragma unroll
        for (int mt = 0; mt < 4; mt++)
            af[mt] = *(const bf16x8*)(As + (wm*64 + mt*16 + l15)*72 + kc*32 + q*8);
        #pragma unroll
        for (int nt = 0; nt < 4; nt++){
            bf16x8 bf_ = *(const bf16x8*)(Bs + (wn*64 + nt*16 + l15)*72 + kc*32 + q*8);
            #pragma unroll
            for (int mt = 0; mt < 4; mt++)
                acc[mt*4+nt] = __builtin_amdgcn_mfma_f32_16x16x32_bf16(af[mt], bf_, acc[mt*4+nt], 0, 0, 0);
        }
    }
    __syncthreads();   // all As/Bs reads done -> overlay Cs
    #pragma unroll
    for (int mt = 0; mt < 4; mt++)
        #pragma unroll
        for (int nt = 0; nt < 4; nt++)
            #pragma unroll
            for (int e = 0; e < 4; e++){
                int row2 = mt*16 + q*4 + e;
                float v = acc[mt*4+nt][e] * msk[wm*64 + row2];
                Cs[w*4608 + row2*72 + nt*16 + l15] = f2bf(v);
            }
    __syncthreads();
    #pragma unroll
    for (int it = 0; it < 8; it++){
        int flat = lane + it*64;               // [0,512)
        int rr = flat >> 3, c8 = flat & 7;
        uint4 v = *(const uint4*)(Cs + w*4608 + rr*72 + c8*8);
        size_t dst = (size_t)(m0 + wm*64 + rr)*8192 + s*4096 + n0 + wn*64 + c8*8;
        *(uint4*)(Tg + dst) = v;
    }
}

// ---------------- radial MLP -> R[z][a][b][h] bf16 (16x16 pair tile per block)
__global__ __launch_bounds__(256,2) void k_radial(
    const float* __restrict__ geom,
    const float* __restrict__ rW1, const float* __restrict__ rb1,
    const float* __restrict__ rW2, const float* __restrict__ rb2,
    unsigned short* __restrict__ Rc)
{
    __shared__ unsigned short H[256*72];      // h1, then R tile
    __shared__ unsigned short Wt[64*72];      // [hout][hin]
    __shared__ float W1s[NBAS*64];
    __shared__ float rb1s[64], rb2s[64];
    __shared__ float pc0s[256], pc1s[256];
    __shared__ int po0s[256], po1s[256];
    __shared__ float gx[16],gy[16],gz[16],hx[16],hy[16],hz[16];

    int tid = threadIdx.x;
    int z = blockIdx.x;
    int ta = blockIdx.y % 12, tb = blockIdx.y / 12;
    int a0 = ta*16, b0 = tb*16;
    int lane = tid & 63, w = tid >> 6, q = lane >> 4, l15 = lane & 15;

    #pragma unroll
    for (int i = 0; i < 10; i++) W1s[tid + i*256] = rW1[tid + i*256];
    // rW2 [hin][hout] fp32 -> Wt[hout][hin] bf16 (coalesced read, LDS scatter)
    #pragma unroll
    for (int it = 0; it < 16; it++){
        int idx = tid + it*256;               // [0,4096)
        int hin = idx >> 6, hout = idx & 63;
        Wt[hout*72 + hin] = f2bf(rW2[idx]);
    }
    if (tid < 64){ rb1s[tid] = rb1[tid]; rb2s[tid] = rb2[tid]; }
    if (tid < 16){
        int g = (z*NATOMS + a0 + tid)*3;
        gx[tid] = geom[g]; gy[tid] = geom[g+1]; gz[tid] = geom[g+2];
    } else if (tid < 32){
        int t2 = tid - 16;
        int g = (z*NATOMS + b0 + t2)*3;
        hx[t2] = geom[g]; hy[t2] = geom[g+1]; hz[t2] = geom[g+2];
    }
    __syncthreads();

    {   // pair coefficients (2-sparse cosine basis)
        int a_l = tid >> 4, b_l = tid & 15;
        float dx = gx[a_l]-hx[b_l], dy = gy[a_l]-hy[b_l], dz = gz[a_l]-hz[b_l];
        float r = sqrtf(dx*dx + dy*dy + dz*dz);
        float u = r * 3.9f;
        int k0 = (int)u;
        float fr = u - (float)k0;
        float cs = __cosf(fr * 1.57079632679489662f);
        float c0 = cs*cs, c1 = 1.f - c0;
        if (k0   >= NBAS) c0 = 0.f;
        if (k0+1 >= NBAS) c1 = 0.f;
        pc0s[tid] = c0; pc1s[tid] = c1;
        po0s[tid] = min(k0, NBAS-1)*64;
        po1s[tid] = min(k0+1, NBAS-1)*64;
    }
    __syncthreads();

    float bias1 = rb1s[lane];
    #pragma unroll 8
    for (int i = 0; i < 64; i++){
        int p = w*64 + i;
        float c0 = pc0s[p], c1 = pc1s[p];
        int o0 = po0s[p], o1 = po1s[p];
        float pre = bias1 + c0*W1s[o0 + lane] + c1*W1s[o1 + lane];
        H[p*72 + lane] = f2bf(sspf(pre));
    }
    __syncthreads();

    f32x4 acc[16];
    #pragma unroll
    for (int i = 0; i < 16; i++) acc[i] = (f32x4){0.f,0.f,0.f,0.f};
    #pragma unroll
    for (int kc = 0; kc < 2; kc++){
        bf16x8 af[4];
        #pragma unroll
        for (int mt = 0; mt < 4; mt++)
            af[mt] = *(const bf16x8*)(H + ((w*4 + mt)*16 + l15)*72 + kc*32 + q*8);
        #pragma unroll
        for (int nt = 0; nt < 4; nt++){
            bf16x8 bf_ = *(const bf16x8*)(Wt + (nt*16 + l15)*72 + kc*32 + q*8);
            #pragma unroll
            for (int mt = 0; mt < 4; mt++)
                acc[mt*4+nt] = __builtin_amdgcn_mfma_f32_16x16x32_bf16(af[mt], bf_, acc[mt*4+nt], 0, 0, 0);
        }
    }
    __syncthreads();
    #pragma unroll
    for (int mt = 0; mt < 4; mt++)
        #pragma unroll
        for (int nt = 0; nt < 4; nt++){
            float b2 = rb2s[nt*16 + l15];
            #pragma unroll
            for (int e = 0; e < 4; e++){
                int p = (w*4 + mt)*16 + q*4 + e;
                H[p*72 + nt*16 + l15] = f2bf(sspf(acc[mt*4+nt][e] + b2));
            }
        }
    __syncthreads();
    // copy R tile out: R[z][a0+a_l][b0+b_l][h]
    #pragma unroll
    for (int it = 0; it < 8; it++){
        int e = tid + it*256;                  // [0,2048) uint4s
        int a_l = e >> 7, b_l = (e >> 3) & 15, h0 = (e & 7)*8;
        uint4 v = *(const uint4*)(H + (a_l*16 + b_l)*72 + h0);
        size_t dst = ((size_t)(z*NATOMS + a0 + a_l)*NATOMS + b0 + b_l)*64 + h0;
        *(uint4*)(Rc + dst) = v;
    }
}

// ---------------- contraction: part[z][kc][a][j2] (bf16) = sum_{k in chunk} R[a][k]*T[k][j2]
__global__ __launch_bounds__(256,2) void k_contract(
    const unsigned short* __restrict__ Rc, const unsigned short* __restrict__ Tc,
    unsigned short* __restrict__ part)
{
    __shared__ unsigned short sm[2*6912 + 2*4608];
    // A buf0 [0,6912) | A buf1 [6912,13824) | B buf0 [13824,18432) | B buf1 [18432,23040)

    int tid = threadIdx.x;
    int zl = blockIdx.x, kc = blockIdx.y;
    int lane = tid & 63, w = tid >> 6, q = lane >> 4, l15 = lane & 15;

    f32x4 acc[24];
    #pragma unroll
    for (int i = 0; i < 24; i++) acc[i] = (f32x4){0.f,0.f,0.f,0.f};

    const size_t Rbase = (size_t)zl*NATOMS*12288;
    const size_t Tbase = (size_t)zl*NATOMS*8192;

    #define STAGE(BUF, KS) { \
        int aoff_ = (BUF)*6912; int boff_ = 13824 + (BUF)*4608; \
        int b_ = kc*6 + ((KS) >> 1); int h0_ = ((KS) & 1)*32; \
        const unsigned short* Ab = Rc + Rbase + (size_t)b_*64 + h0_; \
        _Pragma("unroll") \
        for (int r_ = 0; r_ < 3; r_++){ \
            int idx = tid + r_*256; int a_ = idx >> 2, c8_ = idx & 3; \
            *(uint4*)(sm + aoff_ + a_*36 + c8_*8) = *(const uint4*)(Ab + (size_t)a_*12288 + c8_*8); \
        } \
        const unsigned short* Bb = Tc + Tbase + (size_t)b_*8192 + h0_; \
        _Pragma("unroll") \
        for (int r_ = 0; r_ < 2; r_++){ \
            int idx = tid + r_*256; int j_ = idx >> 2, c8_ = idx & 3; \
            *(uint4*)(sm + boff_ + j_*36 + c8_*8) = *(const uint4*)(Bb + (size_t)j_*64 + c8_*8); \
        } }

    STAGE(0, 0)
    __syncthreads();
    for (int ks = 0; ks < 12; ks++){
        int buf = ks & 1;
        if (ks < 11) STAGE(buf^1, ks+1)
        int aoff = buf*6912, boff = 13824 + buf*4608;
        bf16x8 af[3];
        #pragma unroll
        for (int mt = 0; mt < 3; mt++)
            af[mt] = *(const bf16x8*)(sm + aoff + (w*48 + mt*16 + l15)*36 + q*8);
        #pragma unroll
        for (int nt = 0; nt < 8; nt++){
            bf16x8 bf_ = *(const bf16x8*)(sm + boff + (nt*16 + l15)*36 + q*8);
            #pragma unroll
            for (int mt = 0; mt < 3; mt++)
                acc[mt*8+nt] = __builtin_amdgcn_mfma_f32_16x16x32_bf16(af[mt], bf_, acc[mt*8+nt], 0, 0, 0);
        }
        __syncthreads();
    }
    unsigned short* pbase = part + ((size_t)(zl*NKC + kc)*NATOMS)*128;
    #pragma unroll
    for (int mt = 0; mt < 3; mt++)
        #pragma unroll
        for (int nt = 0; nt < 8; nt++)
            #pragma unroll
            for (int e = 0; e < 4; e++){
                int a = w*48 + mt*16 + q*4 + e;
                int j2 = nt*16 + l15;
                pbase[a*128 + j2] = f2bf(acc[mt*8+nt][e]);
            }
    #undef STAGE
}

// ---------------- reduce partials + sp + mask -> bf16 next features
__global__ void k_reduceB(const unsigned short* __restrict__ part, const float* __restrict__ mask,
                          unsigned short* __restrict__ fb, unsigned short* __restrict__ fc){
    int zl = blockIdx.y;
    int idx = blockIdx.x*256 + threadIdx.x;    // [0, 24576)
    int a = idx >> 7, j2 = idx & 127;
    const unsigned short* p = part + ((size_t)(zl*NKC)*NATOMS + a)*128 + j2;
    float s = 0.f;
    #pragma unroll
    for (int c = 0; c < NKC; c++) s += bf2f(p[(size_t)c*NATOMS*128]);
    int rowg = zl*NATOMS + a;
    float v = spf_act(s) * mask[rowg];
    if (j2 < 64) fb[rowg*64 + j2] = f2bf(v);
    else         fc[rowg*64 + j2 - 64] = f2bf(v);
}

// ---------------- fused head: h1 + BN1 + leaky + h2 + BN2 + leaky + mask -> y2
// one block per atom; BN axes are (z, feat) per atom == block-local
__global__ __launch_bounds__(256) void k_head(
    const unsigned short* __restrict__ fbio, const unsigned short* __restrict__ fch,
    const float* __restrict__ fW1, const float* __restrict__ fb1,
    const float* __restrict__ fW2, const float* __restrict__ fb2,
    const float* __restrict__ mask, float* __restrict__ y2)
{
    __shared__ float X[2048];
    __shared__ float red[16];
    __shared__ float stats[2];
    int a = blockIdx.x, tid = threadIdx.x;
    int lane = tid & 63, w = tid >> 6;

    #pragma unroll
    for (int i = 0; i < 8; i++){
        int idx = tid + i*256; int z = idx >> 7, c = idx & 127;
        int row = z*NATOMS + a;
        X[idx] = (c < 64) ? bf2f(fbio[row*64 + c]) : bf2f(fch[row*64 + c - 64]);
    }
    __syncthreads();
    // h1: 2 float4 outputs per thread
    f32x4 v[2]; float s = 0.f, ss = 0.f;
    #pragma unroll
    for (int i = 0; i < 2; i++){
        int idx4 = tid + i*256; int z = idx4 >> 5, k4 = (idx4 & 31)*4;
        f32x4 acc = { fb1[k4], fb1[k4+1], fb1[k4+2], fb1[k4+3] };
        #pragma unroll 4
        for (int c = 0; c < 128; c++){
            float xv = X[z*128 + c];
            float4 wv = *(const float4*)(fW1 + (size_t)c*128 + k4);
            acc[0] += xv*wv.x; acc[1] += xv*wv.y; acc[2] += xv*wv.z; acc[3] += xv*wv.w;
        }
        v[i] = acc;
        s += acc[0]+acc[1]+acc[2]+acc[3];
        ss += acc[0]*acc[0]+acc[1]*acc[1]+acc[2]*acc[2]+acc[3]*acc[3];
    }
    for (int off = 32; off; off >>= 1){ s += __shfl_down(s, off); ss += __shfl_down(ss, off); }
    if (!lane){ red[w] = s; red[8+w] = ss; }
    __syncthreads();
    if (!tid){
        float S = red[0]+red[1]+red[2]+red[3];
        float SS = red[8]+red[9]+red[10]+red[11];
        float m = S*(1.f/2048.f), var = SS*(1.f/2048.f) - m*m;
        stats[0] = m; stats[1] = rsqrtf(var + 1e-5f);
    }
    __syncthreads();
    float m1 = stats[0], inv1 = stats[1];
    #pragma unroll
    for (int i = 0; i < 2; i++){
        int idx4 = tid + i*256;
        f32x4 t;
        #pragma unroll
        for (int e = 0; e < 4; e++){
            float x = (v[i][e]-m1)*inv1;
            t[e] = (x > 0.f) ? x : 0.2f*x;
        }
        *(f32x4*)(X + idx4*4) = t;
    }
    __syncthreads();
    // h2: 2 outputs per thread
    float u[2]; s = 0.f; ss = 0.f;
    #pragma unroll
    for (int i = 0; i < 2; i++){
        int idx = tid + i*256; int z = idx >> 5, j = idx & 31;
        float acc = fb2[j];
        #pragma unroll 8
        for (int k = 0; k < 128; k++) acc += X[z*128 + k]*fW2[k*32 + j];
        u[i] = acc; s += acc; ss += acc*acc;
    }
    for (int off = 32; off; off >>= 1){ s += __shfl_down(s, off); ss += __shfl_down(ss, off); }
    if (!lane){ red[w] = s; red[8+w] = ss; }
    __syncthreads();
    if (!tid){
        float S = red[0]+red[1]+red[2]+red[3];
        float SS = red[8]+red[9]+red[10]+red[11];
        float m = S*(1.f/512.f), var = SS*(1.f/512.f) - m*m;
        stats[0] = m; stats[1] = rsqrtf(var + 1e-5f);
    }
    __syncthreads();
    float m2 = stats[0], inv2 = stats[1];
    #pragma unroll
    for (int i = 0; i < 2; i++){
        int idx = tid + i*256; int z = idx >> 5, j = idx & 31;
        float x = (u[i]-m2)*inv2;
        x = (x > 0.f) ? x : 0.2f*x;
        y2[(size_t)(z*NATOMS + a)*32 + j] = x * mask[z*NATOMS + a];
    }
}

// ---------------- out[z,j] = sum_a y2[z,a,j]
__global__ void k_sum(const float* __restrict__ y2, float* __restrict__ out){
    int e = blockIdx.x;           // 512 outputs
    int z = e >> 5, jj = e & 31;
    int tid = threadIdx.x;        // 64
    float s = 0.f;
    for (int a = tid; a < NATOMS; a += 64) s += y2[(z*NATOMS + a)*32 + jj];
    for (int off = 32; off; off >>= 1) s += __shfl_down(s, off);
    if (!tid) out[e] = s;
}

extern "C" void kernel_launch(void* const* d_in, const int* in_sizes, int n_in,
                              void* d_out, int out_size, void* d_ws, size_t ws_size,
                              hipStream_t stream){
    const float* features = (const float*)d_in[0];
    const float* geometry = (const float*)d_in[1];
    const float* mask     = (const float*)d_in[2];
    const float* W_bio    = (const float*)d_in[3];
    const float* b_bio    = (const float*)d_in[4];
    const float* W_ch     = (const float*)d_in[5];
    const float* b_ch     = (const float*)d_in[6];
    const float* rW1[2] = {(const float*)d_in[7],  (const float*)d_in[12]};
    const float* rb1[2] = {(const float*)d_in[8],  (const float*)d_in[13]};
    const float* rW2[2] = {(const float*)d_in[9],  (const float*)d_in[14]};
    const float* rb2[2] = {(const float*)d_in[10], (const float*)d_in[15]};
    const float* rWo[2] = {(const float*)d_in[11], (const float*)d_in[16]};
    const float* fW1 = (const float*)d_in[17];
    const float* fb1 = (const float*)d_in[18];
    const float* fW2 = (const float*)d_in[19];
    const float* fb2 = (const float*)d_in[20];

    char* ws = (char*)d_ws;
    unsigned short* fAb = (unsigned short*)ws;   ws += (size_t)ZA*64*2;
    unsigned short* fAc = (unsigned short*)ws;   ws += (size_t)ZA*64*2;
    unsigned short* fBb = (unsigned short*)ws;   ws += (size_t)ZA*64*2;
    unsigned short* fBc = (unsigned short*)ws;   ws += (size_t)ZA*64*2;
    unsigned short* Tg = (unsigned short*)ws;    ws += (size_t)ZA*8192*2;            // 50.3 MB
    unsigned short* Rc = (unsigned short*)ws;    ws += (size_t)ZB*NATOMS*NATOMS*64*2; // 75.5 MB
    unsigned short* part = (unsigned short*)ws;  ws += (size_t)ZB*NKC*NATOMS*128*2;   // 25.2 MB
    float* y2 = (float*)ws;                      ws += (size_t)ZA*32*4;

    dim3 gt(24, 32, 2);
    dim3 gr(ZB, 144);
    dim3 gc(ZB, NKC);
    dim3 gd(96, ZB);
    // layer 0 (encode fused into tmpB)
    k_tmpB<<<gt, 256, 0, stream>>>(nullptr, nullptr, features, W_bio, b_bio, W_ch, b_ch,
                                   mask, rWo[0], Tg);
    k_radial<<<gr, 256, 0, stream>>>(geometry, rW1[0], rb1[0], rW2[0], rb2[0], Rc);
    k_contract<<<gc, 256, 0, stream>>>(Rc, Tg, part);
    k_reduceB<<<gd, 256, 0, stream>>>(part, mask, fAb, fAc);
    // layer 1
    k_tmpB<<<gt, 256, 0, stream>>>(fAb, fAc, nullptr, W_bio, b_bio, W_ch, b_ch,
                                   mask, rWo[1], Tg);
    k_radial<<<gr, 256, 0, stream>>>(geometry, rW1[1], rb1[1], rW2[1], rb2[1], Rc);
    k_contract<<<gc, 256, 0, stream>>>(Rc, Tg, part);
    k_reduceB<<<gd, 256, 0, stream>>>(part, mask, fBb, fBc);
    // fused head + final sum
    k_head<<<NATOMS, 256, 0, stream>>>(fBb, fBc, fW1, fb1, fW2, fb2, mask, y2);
    k_sum<<<512, 64, 0, stream>>>(y2, (float*)d_out);
}